// Round 8
// baseline (158.262 us; speedup 1.0000x reference)
//
#include <hip/hip_runtime.h>
#include <stdint.h>

// Multi-head Hyena conv, MFMA flash-attention form, round 18:
//   S^T[m][l] = sum_d1 v[d1,m]*x1[d1,l]       mfma 16x16x32 (K=8 valid)
//   P[l][m]   = S * k[l-m]   (sliding f32x4 gate window, zero => causal)
//   O^T[d2][l] += x2 . P^T                    mfma 16x16x32 (full K=32)
// Round-18: ONE-ITER OPERAND PREFETCH pipeline in the inner loop.
// Ledger r10-r17: occupancy lever dead (clean builds 38-47% occ, same
// 75-76us; >=6 waves/EU = allocator spill cliff); async staging neutral;
// full unroll spills. r17 showed extra VALU degrades ~1:1 => per-iter
// SERIAL CHAIN bound: ds_read wait (~120cyc) -> S-MFMA lat -> gating ->
// acc-MFMA. This round: issue iter c+32's av/ax/g ds_reads BEFORE iter
// c's compute, consume next iter -- removes the lgkm wait from the chain
// for all iters but the first per chunk. Wrapped index (c+32)&127 makes
// prefetch unconditional (last-iter garbage never consumed; bounds
// verified: en-16 >= 3, prologue max read gwin[254], entry 255 unused).
// Config: (256,4) -- the only clean fast point. Sync v/x2 staging (lower
// pressure than async, measured equal), kg-only async prefetch, raw
// s_barrier + lgkmcnt-only drains, chunk-local gate file.
// Tripwire: WRITE>25MB = spill -> strip g-prefetch. Clean-but-neutral =>
// chain is MFMA-latency+gating => next: 32x32x16 S restructure.
// Shapes fixed by setup: B=2, D=1024, L=2048, NH=8, H=128.

typedef __attribute__((ext_vector_type(8))) short bf16x8;
typedef __attribute__((ext_vector_type(4))) float f32x4;
typedef __attribute__((ext_vector_type(2))) float f32x2;

#define NHd  8
#define SC   128     // m superchunk staged in LDS
#define GW   256     // gate window: l-m spans [l0b-s0-127, l0b-s0+127]

static __device__ __forceinline__ uint32_t pkbf(float a, float b) {
    // RNE-ish pack {bf16(a) lo, bf16(b) hi}; +0x8000 rounds (ties away)
    const uint32_t ua = __float_as_uint(a) + 0x8000u;
    const uint32_t ub = __float_as_uint(b) + 0x8000u;
    return __builtin_amdgcn_perm(ub, ua, 0x07060302u);
}

static __device__ __forceinline__ uint32_t pktr(f32x2 p) {
    // truncation pack: upper 16 bits of each f32 -> {lo,hi} bf16 (1 v_perm)
    union { f32x2 f; uint32_t u[2]; } c; c.f = p;
    return __builtin_amdgcn_perm(c.u[1], c.u[0], 0x07060302u);
}

// gate two S values by two k values: v_pk_mul_f32 + v_perm (2 inst)
static __device__ __forceinline__ uint32_t gmul2(f32x2 s, f32x2 g) {
    return pktr(s * g);
}

union U8 { uint32_t u[4]; bf16x8 v; uint4 q; };

__global__ __launch_bounds__(256, 4) void hyena_mfma18_kernel(
    const float* __restrict__ v, const float* __restrict__ kf,
    const float* __restrict__ bias, const float* __restrict__ x1,
    const float* __restrict__ x2, float* __restrict__ out,
    int B, int H, int L)
{
    __shared__ __align__(16) float4 gwin[GW];           // sliding gate window
    __shared__ __align__(16) ushort vT[2][SC][NHd];     // [b][m][d1] bf16
    __shared__ __align__(16) ushort x2T[2][NHd][136];   // [b][d2][pi(m)] bf16
    __shared__ float sbuf[2][128];                      // skip gate per (b,l)

    const int tid  = threadIdx.x;
    const int h    = blockIdx.x;
    const int l0b  = ((int)gridDim.y - 1 - (int)blockIdx.y) * 128; // big-l first
    const int nk   = l0b + 128;

    const int lane = tid & 63, wv = tid >> 6;
    const int lq   = lane & 15, quad = lane >> 4;
    const int wb   = wv & 1;                // batch handled by this wave
    const int wseg = wv >> 1;               // which 64-l half of the block
    const int wl0  = l0b + wseg * 64;       // wave's 64-l range start
    const int baseb = (wb * H + h) * NHd * L;

    // ---------- fixed staging coordinates ----------
    const int sb_b   = tid >> 7, sb_row = tid & 127;
    const int sb_bs  = (sb_b * H + h) * NHd * L;
    const float* vp0 = v + sb_bs + sb_row;
    const int sb_d2  = sb_row >> 4, sb_ms = (sb_row & 15) * 8;
    const int sb_G   = sb_ms & ~31;                 // 32-group base
    const int sb_o   = sb_ms & 31;                  // 0,8,16,24
    const int sb_pa  = ((sb_o >> 2) & 3) * 8 + (sb_o >> 4) * 4;
    const float* xp0 = x2 + sb_bs + sb_d2 * L + sb_ms;
    const float* kp  = kf + h * L;
    const int gi0    = l0b - 127 + tid;             // k idx of gwin[tid] @ s0=0

    // ---------- k-only async prefetch (4 regs; gwin feed) ----------
    float kg0 = 0.f, kg1 = 0.f, kg2 = 0.f, kg3 = 0.f;
    auto issue_kg = [&](int s0) {
        if (tid < GW - 1) {
            const int i = gi0 - s0;
            if (i >= 3) {
                kg0 = kp[i]; kg1 = kp[i - 1]; kg2 = kp[i - 2]; kg3 = kp[i - 3];
            } else {
                kg0 = kg1 = kg2 = kg3 = 0.f;
                if (i >= 0) kg0 = kp[i];
                if (i >= 1) kg1 = kp[i - 1];
                if (i >= 2) kg2 = kp[i - 2];
            }
        }
    };

    // ---------- prologue ----------
    issue_kg(0);   // chunk-0 k loads fly under xf/sbuf build below

    // xf fragments (mfma1 B operand) for 4 l-subtiles, packed in registers
    bf16x8 xf[4] = {};
    if (quad == 0) {
#pragma unroll
        for (int j = 0; j < 4; ++j) {
            float a0[NHd];
#pragma unroll
            for (int d1 = 0; d1 < NHd; ++d1)
                a0[d1] = x1[baseb + d1 * L + wl0 + 16 * j + lq];
            U8 u0;
#pragma unroll
            for (int t = 0; t < 4; ++t) u0.u[t] = pkbf(a0[2 * t], a0[2 * t + 1]);
            xf[j] = u0.v;
        }
    }

    // skip-term gate, both b, 128 l (all 256 threads)
    {
        const int bb = tid >> 7, l = tid & 127;
        const int bs = (bb * H + h) * NHd * L;
        float s = 0.f;
#pragma unroll
        for (int d1 = 0; d1 < NHd; ++d1)
            s += bias[h * NHd + d1] * x1[bs + d1 * L + l0b + l]
                                    * v [bs + d1 * L + l0b + l];
        sbuf[bb][l] = s;
    }

    f32x4 acc[4];
#pragma unroll
    for (int j = 0; j < 4; ++j) acc[j] = (f32x4){0.f, 0.f, 0.f, 0.f};

    const int wlmax = wl0 + 63;
    // gate window coordinate (s0-independent): e = ebase - c
    const int ebase = 127 + wseg * 64 + lq - 4 * quad;

    for (int s0 = 0; s0 < nk; s0 += SC) {
        // barrier A: previous chunk's LDS readers done. lgkmcnt-only drain;
        // the in-flight kg prefetch is NOT drained.
        asm volatile("s_waitcnt lgkmcnt(0)" ::: "memory");
        __builtin_amdgcn_s_barrier();

        // ---- sync stage vT / x2T (global -> pack -> LDS, this phase) ----
        {
            const float* vp = vp0 + s0;
            const float f0 = vp[0 * L], f1 = vp[1 * L], f2 = vp[2 * L],
                        f3 = vp[3 * L], f4 = vp[4 * L], f5 = vp[5 * L],
                        f6 = vp[6 * L], f7 = vp[7 * L];
            const float4 a0 = *(const float4*)(xp0 + s0);
            const float4 a1 = *(const float4*)(xp0 + s0 + 4);
            *(uint4*)&vT[sb_b][sb_row][0] = make_uint4(
                pkbf(f0, f1), pkbf(f2, f3), pkbf(f4, f5), pkbf(f6, f7));
            *(uint2*)&x2T[sb_b][sb_d2][sb_G + sb_pa] =
                make_uint2(pkbf(a0.x, a0.y), pkbf(a0.z, a0.w));
            *(uint2*)&x2T[sb_b][sb_d2][sb_G + sb_pa + 8] =
                make_uint2(pkbf(a1.x, a1.y), pkbf(a1.z, a1.w));
        }
        // gwin[e] = {k[i],k[i-1],k[i-2],k[i-3]}, i = l0b-s0-127+e, from the
        // kg regs prefetched last chunk. entry 255 never read -> skip.
        if (tid < GW - 1)
            gwin[tid] = make_float4(kg0, kg1, kg2, kg3);

        // ---- issue next chunk's k prefetch (flies under compute) ----
        if (s0 + SC < nk) issue_kg(s0 + SC);

        // barrier B: staging visible (lgkmcnt drains ds_writes; kg loads
        // stay in flight).
        asm volatile("s_waitcnt lgkmcnt(0)" ::: "memory");
        __builtin_amdgcn_s_barrier();

        // ---- chunk compute prologue: load iter c=0 operands ----
        // (gate file is chunk-local: gwin_new[e] = gwin_old[e-128], so the
        // fresh loads reproduce any would-be carry exactly.)
        float4 g4 = *(const float4*)&gwin[ebase + 48];
        float4 g3 = *(const float4*)&gwin[ebase + 32];
        float4 g2 = *(const float4*)&gwin[ebase + 16];
        float4 g1 = *(const float4*)&gwin[ebase];
        float4 g0 = *(const float4*)&gwin[ebase - 16];
        bf16x8 av0 = {}, av1 = {};
        if (quad == 0) {
            av0 = *(const bf16x8*)&vT[wb][lq][0];
            av1 = *(const bf16x8*)&vT[wb][16 + lq][0];
        }
        bf16x8 ax = *(const bf16x8*)&x2T[wb][lq & 7][8 * quad];

        // wave-uniform trip count, multiple of 32 (wseg0: 64 at diagonal)
        const int cmax = min(SC, wlmax - s0 + 1);
        for (int c = 0; c < cmax; c += 32) {
            // ---- prefetch iter c+32 operands (wrapped; last-iter garbage
            // never consumed). In flight under this iter's MFMA+gating. ----
            const int cn = (c + 32) & (SC - 1);
            const int en = ebase - cn;
            bf16x8 av0n = {}, av1n = {};
            if (quad == 0) {
                av0n = *(const bf16x8*)&vT[wb][cn + lq][0];
                av1n = *(const bf16x8*)&vT[wb][cn + 16 + lq][0];
            }
            const bf16x8 axn = *(const bf16x8*)&x2T[wb][lq & 7][cn + 8 * quad];
            const float4 g1n = *(const float4*)&gwin[en];
            const float4 g0n = *(const float4*)&gwin[en - 16];

            const f32x4 Z = {0.f, 0.f, 0.f, 0.f};
            // ---- subtile pair 0,1 ----
            {
                const f32x4 Sa0 = __builtin_amdgcn_mfma_f32_16x16x32_bf16(av0, xf[0], Z, 0, 0, 0);
                const f32x4 Sa1 = __builtin_amdgcn_mfma_f32_16x16x32_bf16(av1, xf[0], Z, 0, 0, 0);
                const f32x4 Sb0 = __builtin_amdgcn_mfma_f32_16x16x32_bf16(av0, xf[1], Z, 0, 0, 0);
                const f32x4 Sb1 = __builtin_amdgcn_mfma_f32_16x16x32_bf16(av1, xf[1], Z, 0, 0, 0);
                U8 p;
                p.u[0] = gmul2((f32x2){Sa0[0], Sa0[1]}, (f32x2){g1.x, g1.y});
                p.u[1] = gmul2((f32x2){Sa0[2], Sa0[3]}, (f32x2){g1.z, g1.w});
                p.u[2] = gmul2((f32x2){Sa1[0], Sa1[1]}, (f32x2){g0.x, g0.y});
                p.u[3] = gmul2((f32x2){Sa1[2], Sa1[3]}, (f32x2){g0.z, g0.w});
                acc[0] = __builtin_amdgcn_mfma_f32_16x16x32_bf16(ax, p.v, acc[0], 0, 0, 0);
                p.u[0] = gmul2((f32x2){Sb0[0], Sb0[1]}, (f32x2){g2.x, g2.y});
                p.u[1] = gmul2((f32x2){Sb0[2], Sb0[3]}, (f32x2){g2.z, g2.w});
                p.u[2] = gmul2((f32x2){Sb1[0], Sb1[1]}, (f32x2){g1.x, g1.y});
                p.u[3] = gmul2((f32x2){Sb1[2], Sb1[3]}, (f32x2){g1.z, g1.w});
                acc[1] = __builtin_amdgcn_mfma_f32_16x16x32_bf16(ax, p.v, acc[1], 0, 0, 0);
            }
            // ---- subtile pair 2,3 ----
            {
                const f32x4 Sc0 = __builtin_amdgcn_mfma_f32_16x16x32_bf16(av0, xf[2], Z, 0, 0, 0);
                const f32x4 Sc1 = __builtin_amdgcn_mfma_f32_16x16x32_bf16(av1, xf[2], Z, 0, 0, 0);
                const f32x4 Sd0 = __builtin_amdgcn_mfma_f32_16x16x32_bf16(av0, xf[3], Z, 0, 0, 0);
                const f32x4 Sd1 = __builtin_amdgcn_mfma_f32_16x16x32_bf16(av1, xf[3], Z, 0, 0, 0);
                U8 p;
                p.u[0] = gmul2((f32x2){Sc0[0], Sc0[1]}, (f32x2){g3.x, g3.y});
                p.u[1] = gmul2((f32x2){Sc0[2], Sc0[3]}, (f32x2){g3.z, g3.w});
                p.u[2] = gmul2((f32x2){Sc1[0], Sc1[1]}, (f32x2){g2.x, g2.y});
                p.u[3] = gmul2((f32x2){Sc1[2], Sc1[3]}, (f32x2){g2.z, g2.w});
                acc[2] = __builtin_amdgcn_mfma_f32_16x16x32_bf16(ax, p.v, acc[2], 0, 0, 0);
                p.u[0] = gmul2((f32x2){Sd0[0], Sd0[1]}, (f32x2){g4.x, g4.y});
                p.u[1] = gmul2((f32x2){Sd0[2], Sd0[3]}, (f32x2){g4.z, g4.w});
                p.u[2] = gmul2((f32x2){Sd1[0], Sd1[1]}, (f32x2){g3.x, g3.y});
                p.u[3] = gmul2((f32x2){Sd1[2], Sd1[3]}, (f32x2){g3.z, g3.w});
                acc[3] = __builtin_amdgcn_mfma_f32_16x16x32_bf16(ax, p.v, acc[3], 0, 0, 0);
            }

            // ---- rotate: next iter consumes prefetched operands ----
            g4 = g2; g3 = g1; g2 = g0; g1 = g1n; g0 = g0n;
            av0 = av0n; av1 = av1n; ax = axn;
        }
    }

    // ---------- epilogue: O^T layout: lane (quad,lq): d2 = 4*quad+r, l = lq ----
    if (quad < 2) {
#pragma unroll
        for (int j = 0; j < 4; ++j) {
            const int lA  = wl0 + 16 * j + lq;
            const float sb = sbuf[wb][wseg * 64 + 16 * j + lq];
#pragma unroll
            for (int r = 0; r < 4; ++r) {
                const int ro = baseb + (4 * quad + r) * L + lA;
                out[ro] = acc[j][r] + x2[ro] * sb;
            }
        }
    }
}

extern "C" void kernel_launch(void* const* d_in, const int* in_sizes, int n_in,
                              void* d_out, int out_size, void* d_ws, size_t ws_size,
                              hipStream_t stream) {
    const float* v    = (const float*)d_in[0];
    const float* k    = (const float*)d_in[1];
    const float* bias = (const float*)d_in[2];
    const float* x1   = (const float*)d_in[3];
    const float* x2   = (const float*)d_in[4];
    float* out = (float*)d_out;

    const int D = in_sizes[2];            // 1024
    const int H = D / NHd;                // 128
    const int L = in_sizes[1] / H;        // 2048
    const int B = in_sizes[0] / (D * L);  // 2

    dim3 grid(H, L / 128);
    hyena_mfma18_kernel<<<grid, 256, 0, stream>>>(v, k, bias, x1, x2, out, B, H, L);
}

// Round 9
// 145.631 us; speedup vs baseline: 1.0867x; 1.0867x over previous
//
#include <hip/hip_runtime.h>
#include <stdint.h>

// Multi-head Hyena conv, MFMA flash-attention form, round 19:
//   S^T[m][l] = sum_d1 v[d1,m]*x1[d1,l]       mfma 16x16x16 (K=8 valid)
//   P[l][m]   = S * k[l-m]   (sliding f32x4 gate window, zero => causal)
//   O^T[d2][l] += x2 . P^T                    mfma 16x16x32 (full K=32)
// Round-19: S-MFMA shape 16x16x32 -> 16x16x16 (legacy op, carried on
// gfx950, ISA sec.10). d1=8 means K=8 valid: the old shape wasted 75% of
// K at 16 issue-cyc; the new wastes 50% at 8 cyc. Same 16x16 C layout
// (shape-determined) => gating/PV/epilogue UNCHANGED. A/B frags halve
// (av0/av1 4->2 regs, xf 16->8): -12 regs of body working set, which is
// the real target -- at the 64-VGPR allocation the scheduler serializes
// the subtile-pair sub-chains for lack of registers (r17/r18: +VALU =
// +time 1:1; occupancy capped at 16 waves/CU by VGPR=64 per m69 ladder,
// lower VGPR = spill cliff r15/r16). A/B k-map: k=4*(lane>>4)+i =>
// quads 0-1 carry d1 0..7, quads 2-3 zero.
// Base = r13 exactly (best clean: 75.5us/dispatch): async v/x2/k stage
// split, carried gate file, (256,4), raw s_barrier + lgkmcnt-only
// drains, rolling inner loop (r14 unroll and r18 prefetch both = -8%).
// Tripwire: WRITE>25MB = spill -> revert frag change. Neutral => chain
// is gating-VALU bound -> plateau assessment.
// Shapes fixed by setup: B=2, D=1024, L=2048, NH=8, H=128.

typedef __attribute__((ext_vector_type(8))) short bf16x8;
typedef __attribute__((ext_vector_type(4))) short bf16x4;
typedef __attribute__((ext_vector_type(4))) float f32x4;
typedef __attribute__((ext_vector_type(2))) float f32x2;

#define NHd  8
#define SC   128     // m superchunk staged in LDS
#define GW   256     // gate window: l-m spans [l0b-s0-127, l0b-s0+127]

static __device__ __forceinline__ uint32_t pkbf(float a, float b) {
    // RNE-ish pack {bf16(a) lo, bf16(b) hi}; +0x8000 rounds (ties away)
    const uint32_t ua = __float_as_uint(a) + 0x8000u;
    const uint32_t ub = __float_as_uint(b) + 0x8000u;
    return __builtin_amdgcn_perm(ub, ua, 0x07060302u);
}

static __device__ __forceinline__ uint32_t pktr(f32x2 p) {
    // truncation pack: upper 16 bits of each f32 -> {lo,hi} bf16 (1 v_perm)
    union { f32x2 f; uint32_t u[2]; } c; c.f = p;
    return __builtin_amdgcn_perm(c.u[1], c.u[0], 0x07060302u);
}

// gate two S values by two k values: v_pk_mul_f32 + v_perm (2 inst)
static __device__ __forceinline__ uint32_t gmul2(f32x2 s, f32x2 g) {
    return pktr(s * g);
}

// S-MFMA: 16x16x16 bf16 (K=8 valid). Same C layout as 16x16x32 family.
static __device__ __forceinline__ f32x4 mfmaS(bf16x4 a, bf16x4 b, f32x4 c) {
#if __has_builtin(__builtin_amdgcn_mfma_f32_16x16x16bf16_1k)
    return __builtin_amdgcn_mfma_f32_16x16x16bf16_1k(a, b, c, 0, 0, 0);
#else
    f32x4 d;
    asm("v_mfma_f32_16x16x16_bf16 %0, %1, %2, %3"
        : "=v"(d) : "v"(a), "v"(b), "v"(c));
    return d;
#endif
}

union U8 { uint32_t u[4]; bf16x8 v; uint4 q; };
union U4 { uint32_t u[2]; bf16x4 v; };

__global__ __launch_bounds__(256, 4) void hyena_mfma19_kernel(
    const float* __restrict__ v, const float* __restrict__ kf,
    const float* __restrict__ bias, const float* __restrict__ x1,
    const float* __restrict__ x2, float* __restrict__ out,
    int B, int H, int L)
{
    __shared__ __align__(16) float4 gwin[GW];           // sliding gate window
    __shared__ __align__(16) ushort vT[2][SC][NHd];     // [b][m][d1] bf16
    __shared__ __align__(16) ushort x2T[2][NHd][136];   // [b][d2][pi(m)] bf16
    __shared__ float sbuf[2][128];                      // skip gate per (b,l)

    const int tid  = threadIdx.x;
    const int h    = blockIdx.x;
    const int l0b  = ((int)gridDim.y - 1 - (int)blockIdx.y) * 128; // big-l first
    const int nk   = l0b + 128;

    const int lane = tid & 63, wv = tid >> 6;
    const int lq   = lane & 15, quad = lane >> 4;
    const int wb   = wv & 1;                // batch handled by this wave
    const int wseg = wv >> 1;               // which 64-l half of the block
    const int wl0  = l0b + wseg * 64;       // wave's 64-l range start
    const int baseb = (wb * H + h) * NHd * L;

    // ---------- fixed staging coordinates ----------
    const int sb_b   = tid >> 7, sb_row = tid & 127;
    const int sb_bs  = (sb_b * H + h) * NHd * L;
    const float* vp0 = v + sb_bs + sb_row;
    const int sb_d2  = sb_row >> 4, sb_ms = (sb_row & 15) * 8;
    const int sb_G   = sb_ms & ~31;                 // 32-group base
    const int sb_o   = sb_ms & 31;                  // 0,8,16,24
    const int sb_pa  = ((sb_o >> 2) & 3) * 8 + (sb_o >> 4) * 4;
    const float* xp0 = x2 + sb_bs + sb_d2 * L + sb_ms;
    const float* kp  = kf + h * L;
    const int gi0    = l0b - 127 + tid;             // k idx of gwin[tid] @ s0=0

    // ---------- async stage registers (one chunk in flight) ----------
    float  fv0, fv1, fv2, fv3, fv4, fv5, fv6, fv7;  // v column, 8 x d1
    float4 q0, q1;                                   // x2 8-run
    float  kg0 = 0.f, kg1 = 0.f, kg2 = 0.f, kg3 = 0.f; // gate window entry

    auto issue_stage = [&](int s0) {
        const float* vp = vp0 + s0;
        fv0 = vp[0 * L]; fv1 = vp[1 * L]; fv2 = vp[2 * L]; fv3 = vp[3 * L];
        fv4 = vp[4 * L]; fv5 = vp[5 * L]; fv6 = vp[6 * L]; fv7 = vp[7 * L];
        q0 = *(const float4*)(xp0 + s0);
        q1 = *(const float4*)(xp0 + s0 + 4);
        if (tid < GW - 1) {
            const int i = gi0 - s0;
            if (i >= 3) {
                kg0 = kp[i]; kg1 = kp[i - 1]; kg2 = kp[i - 2]; kg3 = kp[i - 3];
            } else {
                kg0 = kg1 = kg2 = kg3 = 0.f;
                if (i >= 0) kg0 = kp[i];
                if (i >= 1) kg1 = kp[i - 1];
                if (i >= 2) kg2 = kp[i - 2];
            }
        }
    };

    // ---------- prologue ----------
    issue_stage(0);   // chunk-0 loads fly under xf/sbuf build below

    // xf fragments (S-MFMA B operand, 16x16x16: k=4*(lane>>4)+i) for 4
    // l-subtiles. Quads 0-1 carry d1 = 4*quad+t; quads 2-3 zero.
    bf16x4 xf[4] = {};
    if (quad < 2) {
#pragma unroll
        for (int j = 0; j < 4; ++j) {
            float a0[4];
#pragma unroll
            for (int t = 0; t < 4; ++t)
                a0[t] = x1[baseb + (4 * quad + t) * L + wl0 + 16 * j + lq];
            U4 u0;
            u0.u[0] = pkbf(a0[0], a0[1]);
            u0.u[1] = pkbf(a0[2], a0[3]);
            xf[j] = u0.v;
        }
    }

    // skip-term gate, both b, 128 l (all 256 threads)
    {
        const int bb = tid >> 7, l = tid & 127;
        const int bs = (bb * H + h) * NHd * L;
        float s = 0.f;
#pragma unroll
        for (int d1 = 0; d1 < NHd; ++d1)
            s += bias[h * NHd + d1] * x1[bs + d1 * L + l0b + l]
                                    * v [bs + d1 * L + l0b + l];
        sbuf[bb][l] = s;
    }

    f32x4 acc[4];
#pragma unroll
    for (int j = 0; j < 4; ++j) acc[j] = (f32x4){0.f, 0.f, 0.f, 0.f};

    const int wlmax = wl0 + 63;
    // gate window coordinate (s0-independent): e = ebase - c
    const int ebase = 127 + wseg * 64 + lq - 4 * quad;

    bool gfirst = true;
    float4 g0, g1, g2, g3, g4;   // 5-deep gate file; carries across s0 too

    for (int s0 = 0; s0 < nk; s0 += SC) {
        // barrier A: previous chunk's LDS readers done. Own ds ops drained via
        // lgkmcnt only -- async global loads stay in flight (no vmcnt drain).
        asm volatile("s_waitcnt lgkmcnt(0)" ::: "memory");
        __builtin_amdgcn_s_barrier();

        // ---- write-late: pack staged regs, ds_write ----
        *(uint4*)&vT[sb_b][sb_row][0] = make_uint4(
            pkbf(fv0, fv1), pkbf(fv2, fv3), pkbf(fv4, fv5), pkbf(fv6, fv7));
        *(uint2*)&x2T[sb_b][sb_d2][sb_G + sb_pa] =
            make_uint2(pkbf(q0.x, q0.y), pkbf(q0.z, q0.w));
        *(uint2*)&x2T[sb_b][sb_d2][sb_G + sb_pa + 8] =
            make_uint2(pkbf(q1.x, q1.y), pkbf(q1.z, q1.w));
        // gwin[e] = {k[i],k[i-1],k[i-2],k[i-3]}, i = l0b-s0-127+e; entry 255
        // never read (max read index 254) -> skip.
        if (tid < GW - 1)
            gwin[tid] = make_float4(kg0, kg1, kg2, kg3);

        // ---- issue-early: next chunk's global loads fly under compute ----
        if (s0 + SC < nk) issue_stage(s0 + SC);

        // barrier B: staging visible. ds_writes drained via lgkmcnt; the
        // just-issued global loads are NOT drained.
        asm volatile("s_waitcnt lgkmcnt(0)" ::: "memory");
        __builtin_amdgcn_s_barrier();

        // wave-uniform trip count, multiple of 32 (wseg0: 64 at diagonal)
        const int cmax = min(SC, wlmax - s0 + 1);
        for (int c = 0; c < cmax; c += 32) {
            const int e = ebase - c;

            // ---- loads first (independent) ----
            // A frag (16x16x16): row=lane&15, k=4*(lane>>4)+i -> quads 0-1
            // read d1 = 4*quad..4*quad+3 (8B each); quads 2-3 zero.
            bf16x4 av0 = {}, av1 = {};
            if (quad < 2) {
                av0 = *(const bf16x4*)&vT[wb][c + lq][quad * 4];
                av1 = *(const bf16x4*)&vT[wb][c + 16 + lq][quad * 4];
            }
            // gate file: subtile j: lo = g(e+16j), hi = g(e+16j-16)
            if (gfirst) {
                g4 = *(const float4*)&gwin[e + 48];
                g3 = *(const float4*)&gwin[e + 32];
                g2 = *(const float4*)&gwin[e + 16];
                gfirst = false;
            } else { g4 = g2; g3 = g1; g2 = g0; }
            g1 = *(const float4*)&gwin[e];
            g0 = *(const float4*)&gwin[e - 16];
            const bf16x8 ax = *(const bf16x8*)&x2T[wb][lq & 7][c + 8 * quad];

            const f32x4 Z = {0.f, 0.f, 0.f, 0.f};
            // ---- subtile pair 0,1 ----
            {
                const f32x4 Sa0 = mfmaS(av0, xf[0], Z);
                const f32x4 Sa1 = mfmaS(av1, xf[0], Z);
                const f32x4 Sb0 = mfmaS(av0, xf[1], Z);
                const f32x4 Sb1 = mfmaS(av1, xf[1], Z);
                U8 p;
                p.u[0] = gmul2((f32x2){Sa0[0], Sa0[1]}, (f32x2){g1.x, g1.y});
                p.u[1] = gmul2((f32x2){Sa0[2], Sa0[3]}, (f32x2){g1.z, g1.w});
                p.u[2] = gmul2((f32x2){Sa1[0], Sa1[1]}, (f32x2){g0.x, g0.y});
                p.u[3] = gmul2((f32x2){Sa1[2], Sa1[3]}, (f32x2){g0.z, g0.w});
                acc[0] = __builtin_amdgcn_mfma_f32_16x16x32_bf16(ax, p.v, acc[0], 0, 0, 0);
                p.u[0] = gmul2((f32x2){Sb0[0], Sb0[1]}, (f32x2){g2.x, g2.y});
                p.u[1] = gmul2((f32x2){Sb0[2], Sb0[3]}, (f32x2){g2.z, g2.w});
                p.u[2] = gmul2((f32x2){Sb1[0], Sb1[1]}, (f32x2){g1.x, g1.y});
                p.u[3] = gmul2((f32x2){Sb1[2], Sb1[3]}, (f32x2){g1.z, g1.w});
                acc[1] = __builtin_amdgcn_mfma_f32_16x16x32_bf16(ax, p.v, acc[1], 0, 0, 0);
            }
            // ---- subtile pair 2,3 ----
            {
                const f32x4 Sc0 = mfmaS(av0, xf[2], Z);
                const f32x4 Sc1 = mfmaS(av1, xf[2], Z);
                const f32x4 Sd0 = mfmaS(av0, xf[3], Z);
                const f32x4 Sd1 = mfmaS(av1, xf[3], Z);
                U8 p;
                p.u[0] = gmul2((f32x2){Sc0[0], Sc0[1]}, (f32x2){g3.x, g3.y});
                p.u[1] = gmul2((f32x2){Sc0[2], Sc0[3]}, (f32x2){g3.z, g3.w});
                p.u[2] = gmul2((f32x2){Sc1[0], Sc1[1]}, (f32x2){g2.x, g2.y});
                p.u[3] = gmul2((f32x2){Sc1[2], Sc1[3]}, (f32x2){g2.z, g2.w});
                acc[2] = __builtin_amdgcn_mfma_f32_16x16x32_bf16(ax, p.v, acc[2], 0, 0, 0);
                p.u[0] = gmul2((f32x2){Sd0[0], Sd0[1]}, (f32x2){g4.x, g4.y});
                p.u[1] = gmul2((f32x2){Sd0[2], Sd0[3]}, (f32x2){g4.z, g4.w});
                p.u[2] = gmul2((f32x2){Sd1[0], Sd1[1]}, (f32x2){g3.x, g3.y});
                p.u[3] = gmul2((f32x2){Sd1[2], Sd1[3]}, (f32x2){g3.z, g3.w});
                acc[3] = __builtin_amdgcn_mfma_f32_16x16x32_bf16(ax, p.v, acc[3], 0, 0, 0);
            }
        }
    }

    // ---------- epilogue: O^T layout: lane (quad,lq): d2 = 4*quad+r, l = lq ----
    if (quad < 2) {
#pragma unroll
        for (int j = 0; j < 4; ++j) {
            const int lA  = wl0 + 16 * j + lq;
            const float sb = sbuf[wb][wseg * 64 + 16 * j + lq];
#pragma unroll
            for (int r = 0; r < 4; ++r) {
                const int ro = baseb + (4 * quad + r) * L + lA;
                out[ro] = acc[j][r] + x2[ro] * sb;
            }
        }
    }
}

extern "C" void kernel_launch(void* const* d_in, const int* in_sizes, int n_in,
                              void* d_out, int out_size, void* d_ws, size_t ws_size,
                              hipStream_t stream) {
    const float* v    = (const float*)d_in[0];
    const float* k    = (const float*)d_in[1];
    const float* bias = (const float*)d_in[2];
    const float* x1   = (const float*)d_in[3];
    const float* x2   = (const float*)d_in[4];
    float* out = (float*)d_out;

    const int D = in_sizes[2];            // 1024
    const int H = D / NHd;                // 128
    const int L = in_sizes[1] / H;        // 2048
    const int B = in_sizes[0] / (D * L);  // 2

    dim3 grid(H, L / 128);
    hyena_mfma19_kernel<<<grid, 256, 0, stream>>>(v, k, bias, x1, x2, out, B, H, L);
}

// Round 10
// 144.824 us; speedup vs baseline: 1.0928x; 1.0056x over previous
//
#include <hip/hip_runtime.h>
#include <stdint.h>

// Multi-head Hyena conv, MFMA flash-attention form, round 20:
//   S^T[m][l] = sum_d1 v[d1,m]*x1[d1,l]       mfma 16x16x16 (K=8 valid)
//   P[l][m]   = S * k[l-m]   (sliding f32x4 gate window, zero => causal)
//   O^T[d2][l] += x2 . P^T                    mfma 16x16x32 (full K=32)
// Round-20: DOUBLE-BUFFERED LDS, ONE barrier per superchunk (was 2).
// r19 (best, 72.5us): the 16x16x16 S-swap won ~4% purely via -12 regs of
// working set (MFMA busy cycles UNCHANGED -- 16x16x16 costs the same pipe
// cycles as 16x16x32 on gfx950, both 4-pass). Confirms chain/slack-bound.
// Per-SIMD accounting: 655 cyc wall/iter vs ~350 in-iter chain -> residue
// is the chunk boundary (2 barrier+drain rendezvous per chunk). Dbuf
// removes one: [write regs->buf[n&1]; issue loads n+1; drain; barrier;
// compute buf[n&1]]. Hazards: WAR on buf[n&1] vs compute n-2 safe (all
// waves passed barrier n-1 which follows their compute n-2); concurrent
// compute n-1 reads buf[(n-1)&1]. LDS 13.8->25.7KB (still 4 blocks/CU at
// the VGPR limit). Carried gate file unchanged (carries in REGISTERS;
// e-coordinate is s0-independent).
// Config: (256,4), async stage regs (v8+x2x8+k4), rolling inner loop,
// 16x16x16 S (quads 0-1), v_pk_mul+v_perm gating -- all r19.
// Tripwire: WRITE>25MB = spill -> revert to r19. Neutral => boundary is
// staging-VALU, chain plateau -> roofline assessment.
// Shapes fixed by setup: B=2, D=1024, L=2048, NH=8, H=128.

typedef __attribute__((ext_vector_type(8))) short bf16x8;
typedef __attribute__((ext_vector_type(4))) short bf16x4;
typedef __attribute__((ext_vector_type(4))) float f32x4;
typedef __attribute__((ext_vector_type(2))) float f32x2;

#define NHd  8
#define SC   128     // m superchunk staged in LDS
#define GW   256     // gate window: l-m spans [l0b-s0-127, l0b-s0+127]

static __device__ __forceinline__ uint32_t pkbf(float a, float b) {
    // RNE-ish pack {bf16(a) lo, bf16(b) hi}; +0x8000 rounds (ties away)
    const uint32_t ua = __float_as_uint(a) + 0x8000u;
    const uint32_t ub = __float_as_uint(b) + 0x8000u;
    return __builtin_amdgcn_perm(ub, ua, 0x07060302u);
}

static __device__ __forceinline__ uint32_t pktr(f32x2 p) {
    // truncation pack: upper 16 bits of each f32 -> {lo,hi} bf16 (1 v_perm)
    union { f32x2 f; uint32_t u[2]; } c; c.f = p;
    return __builtin_amdgcn_perm(c.u[1], c.u[0], 0x07060302u);
}

// gate two S values by two k values: v_pk_mul_f32 + v_perm (2 inst)
static __device__ __forceinline__ uint32_t gmul2(f32x2 s, f32x2 g) {
    return pktr(s * g);
}

// S-MFMA: 16x16x16 bf16 (K=8 valid). Same C layout as 16x16x32 family.
static __device__ __forceinline__ f32x4 mfmaS(bf16x4 a, bf16x4 b, f32x4 c) {
#if __has_builtin(__builtin_amdgcn_mfma_f32_16x16x16bf16_1k)
    return __builtin_amdgcn_mfma_f32_16x16x16bf16_1k(a, b, c, 0, 0, 0);
#else
    f32x4 d;
    asm("v_mfma_f32_16x16x16_bf16 %0, %1, %2, %3"
        : "=v"(d) : "v"(a), "v"(b), "v"(c));
    return d;
#endif
}

union U8 { uint32_t u[4]; bf16x8 v; uint4 q; };
union U4 { uint32_t u[2]; bf16x4 v; };

__global__ __launch_bounds__(256, 4) void hyena_mfma20_kernel(
    const float* __restrict__ v, const float* __restrict__ kf,
    const float* __restrict__ bias, const float* __restrict__ x1,
    const float* __restrict__ x2, float* __restrict__ out,
    int B, int H, int L)
{
    __shared__ __align__(16) float4 gwin[2][GW];         // dbuf gate window
    __shared__ __align__(16) ushort vT[2][2][SC][NHd];   // [buf][b][m][d1]
    __shared__ __align__(16) ushort x2T[2][2][NHd][136]; // [buf][b][d2][pi(m)]
    __shared__ float sbuf[2][128];                       // skip gate per (b,l)

    const int tid  = threadIdx.x;
    const int h    = blockIdx.x;
    const int l0b  = ((int)gridDim.y - 1 - (int)blockIdx.y) * 128; // big-l first
    const int nk   = l0b + 128;

    const int lane = tid & 63, wv = tid >> 6;
    const int lq   = lane & 15, quad = lane >> 4;
    const int wb   = wv & 1;                // batch handled by this wave
    const int wseg = wv >> 1;               // which 64-l half of the block
    const int wl0  = l0b + wseg * 64;       // wave's 64-l range start
    const int baseb = (wb * H + h) * NHd * L;

    // ---------- fixed staging coordinates ----------
    const int sb_b   = tid >> 7, sb_row = tid & 127;
    const int sb_bs  = (sb_b * H + h) * NHd * L;
    const float* vp0 = v + sb_bs + sb_row;
    const int sb_d2  = sb_row >> 4, sb_ms = (sb_row & 15) * 8;
    const int sb_G   = sb_ms & ~31;                 // 32-group base
    const int sb_o   = sb_ms & 31;                  // 0,8,16,24
    const int sb_pa  = ((sb_o >> 2) & 3) * 8 + (sb_o >> 4) * 4;
    const float* xp0 = x2 + sb_bs + sb_d2 * L + sb_ms;
    const float* kp  = kf + h * L;
    const int gi0    = l0b - 127 + tid;             // k idx of gwin[tid] @ s0=0

    // ---------- async stage registers (one chunk in flight) ----------
    float  fv0, fv1, fv2, fv3, fv4, fv5, fv6, fv7;  // v column, 8 x d1
    float4 q0, q1;                                   // x2 8-run
    float  kg0 = 0.f, kg1 = 0.f, kg2 = 0.f, kg3 = 0.f; // gate window entry

    auto issue_stage = [&](int s0) {
        const float* vp = vp0 + s0;
        fv0 = vp[0 * L]; fv1 = vp[1 * L]; fv2 = vp[2 * L]; fv3 = vp[3 * L];
        fv4 = vp[4 * L]; fv5 = vp[5 * L]; fv6 = vp[6 * L]; fv7 = vp[7 * L];
        q0 = *(const float4*)(xp0 + s0);
        q1 = *(const float4*)(xp0 + s0 + 4);
        if (tid < GW - 1) {
            const int i = gi0 - s0;
            if (i >= 3) {
                kg0 = kp[i]; kg1 = kp[i - 1]; kg2 = kp[i - 2]; kg3 = kp[i - 3];
            } else {
                kg0 = kg1 = kg2 = kg3 = 0.f;
                if (i >= 0) kg0 = kp[i];
                if (i >= 1) kg1 = kp[i - 1];
                if (i >= 2) kg2 = kp[i - 2];
            }
        }
    };

    // ---------- prologue ----------
    issue_stage(0);   // chunk-0 loads fly under xf/sbuf build below

    // xf fragments (S-MFMA B operand, 16x16x16: k=4*(lane>>4)+i) for 4
    // l-subtiles. Quads 0-1 carry d1 = 4*quad+t; quads 2-3 zero.
    bf16x4 xf[4] = {};
    if (quad < 2) {
#pragma unroll
        for (int j = 0; j < 4; ++j) {
            float a0[4];
#pragma unroll
            for (int t = 0; t < 4; ++t)
                a0[t] = x1[baseb + (4 * quad + t) * L + wl0 + 16 * j + lq];
            U4 u0;
            u0.u[0] = pkbf(a0[0], a0[1]);
            u0.u[1] = pkbf(a0[2], a0[3]);
            xf[j] = u0.v;
        }
    }

    // skip-term gate, both b, 128 l (all 256 threads)
    {
        const int bb = tid >> 7, l = tid & 127;
        const int bs = (bb * H + h) * NHd * L;
        float s = 0.f;
#pragma unroll
        for (int d1 = 0; d1 < NHd; ++d1)
            s += bias[h * NHd + d1] * x1[bs + d1 * L + l0b + l]
                                    * v [bs + d1 * L + l0b + l];
        sbuf[bb][l] = s;
    }

    f32x4 acc[4];
#pragma unroll
    for (int j = 0; j < 4; ++j) acc[j] = (f32x4){0.f, 0.f, 0.f, 0.f};

    const int wlmax = wl0 + 63;
    // gate window coordinate (s0-independent): e = ebase - c
    const int ebase = 127 + wseg * 64 + lq - 4 * quad;

    bool gfirst = true;
    float4 g0, g1, g2, g3, g4;   // 5-deep gate file; carries across s0 too

    for (int s0 = 0, n = 0; s0 < nk; s0 += SC, ++n) {
        const int p = n & 1;

        // ---- write-late: stage regs (chunk n's data) -> buf p ----
        // WAR-safe: all waves passed barrier n-1, which follows their
        // compute n-2 (the last reader of buf p). Concurrent compute n-1
        // reads buf p^1.
        *(uint4*)&vT[p][sb_b][sb_row][0] = make_uint4(
            pkbf(fv0, fv1), pkbf(fv2, fv3), pkbf(fv4, fv5), pkbf(fv6, fv7));
        *(uint2*)&x2T[p][sb_b][sb_d2][sb_G + sb_pa] =
            make_uint2(pkbf(q0.x, q0.y), pkbf(q0.z, q0.w));
        *(uint2*)&x2T[p][sb_b][sb_d2][sb_G + sb_pa + 8] =
            make_uint2(pkbf(q1.x, q1.y), pkbf(q1.z, q1.w));
        // gwin[p][e] = {k[i],k[i-1],k[i-2],k[i-3]}, i = l0b-s0-127+e;
        // entry 255 never read (max read index 254) -> skip.
        if (tid < GW - 1)
            gwin[p][tid] = make_float4(kg0, kg1, kg2, kg3);

        // ---- issue-early: next chunk's global loads fly under compute ----
        if (s0 + SC < nk) issue_stage(s0 + SC);

        // ---- single barrier: staging visible; global loads NOT drained ----
        asm volatile("s_waitcnt lgkmcnt(0)" ::: "memory");
        __builtin_amdgcn_s_barrier();

        // wave-uniform trip count, multiple of 32 (wseg0: 64 at diagonal)
        const int cmax = min(SC, wlmax - s0 + 1);
        for (int c = 0; c < cmax; c += 32) {
            const int e = ebase - c;

            // ---- loads first (independent) ----
            // A frag (16x16x16): row=lane&15, k=4*(lane>>4)+i -> quads 0-1
            // read d1 = 4*quad..4*quad+3 (8B each); quads 2-3 zero.
            bf16x4 av0 = {}, av1 = {};
            if (quad < 2) {
                av0 = *(const bf16x4*)&vT[p][wb][c + lq][quad * 4];
                av1 = *(const bf16x4*)&vT[p][wb][c + 16 + lq][quad * 4];
            }
            // gate file: subtile j: lo = g(e+16j), hi = g(e+16j-16)
            if (gfirst) {
                g4 = *(const float4*)&gwin[p][e + 48];
                g3 = *(const float4*)&gwin[p][e + 32];
                g2 = *(const float4*)&gwin[p][e + 16];
                gfirst = false;
            } else { g4 = g2; g3 = g1; g2 = g0; }
            g1 = *(const float4*)&gwin[p][e];
            g0 = *(const float4*)&gwin[p][e - 16];
            const bf16x8 ax = *(const bf16x8*)&x2T[p][wb][lq & 7][c + 8 * quad];

            const f32x4 Z = {0.f, 0.f, 0.f, 0.f};
            // ---- subtile pair 0,1 ----
            {
                const f32x4 Sa0 = mfmaS(av0, xf[0], Z);
                const f32x4 Sa1 = mfmaS(av1, xf[0], Z);
                const f32x4 Sb0 = mfmaS(av0, xf[1], Z);
                const f32x4 Sb1 = mfmaS(av1, xf[1], Z);
                U8 p2;
                p2.u[0] = gmul2((f32x2){Sa0[0], Sa0[1]}, (f32x2){g1.x, g1.y});
                p2.u[1] = gmul2((f32x2){Sa0[2], Sa0[3]}, (f32x2){g1.z, g1.w});
                p2.u[2] = gmul2((f32x2){Sa1[0], Sa1[1]}, (f32x2){g0.x, g0.y});
                p2.u[3] = gmul2((f32x2){Sa1[2], Sa1[3]}, (f32x2){g0.z, g0.w});
                acc[0] = __builtin_amdgcn_mfma_f32_16x16x32_bf16(ax, p2.v, acc[0], 0, 0, 0);
                p2.u[0] = gmul2((f32x2){Sb0[0], Sb0[1]}, (f32x2){g2.x, g2.y});
                p2.u[1] = gmul2((f32x2){Sb0[2], Sb0[3]}, (f32x2){g2.z, g2.w});
                p2.u[2] = gmul2((f32x2){Sb1[0], Sb1[1]}, (f32x2){g1.x, g1.y});
                p2.u[3] = gmul2((f32x2){Sb1[2], Sb1[3]}, (f32x2){g1.z, g1.w});
                acc[1] = __builtin_amdgcn_mfma_f32_16x16x32_bf16(ax, p2.v, acc[1], 0, 0, 0);
            }
            // ---- subtile pair 2,3 ----
            {
                const f32x4 Sc0 = mfmaS(av0, xf[2], Z);
                const f32x4 Sc1 = mfmaS(av1, xf[2], Z);
                const f32x4 Sd0 = mfmaS(av0, xf[3], Z);
                const f32x4 Sd1 = mfmaS(av1, xf[3], Z);
                U8 p2;
                p2.u[0] = gmul2((f32x2){Sc0[0], Sc0[1]}, (f32x2){g3.x, g3.y});
                p2.u[1] = gmul2((f32x2){Sc0[2], Sc0[3]}, (f32x2){g3.z, g3.w});
                p2.u[2] = gmul2((f32x2){Sc1[0], Sc1[1]}, (f32x2){g2.x, g2.y});
                p2.u[3] = gmul2((f32x2){Sc1[2], Sc1[3]}, (f32x2){g2.z, g2.w});
                acc[2] = __builtin_amdgcn_mfma_f32_16x16x32_bf16(ax, p2.v, acc[2], 0, 0, 0);
                p2.u[0] = gmul2((f32x2){Sd0[0], Sd0[1]}, (f32x2){g4.x, g4.y});
                p2.u[1] = gmul2((f32x2){Sd0[2], Sd0[3]}, (f32x2){g4.z, g4.w});
                p2.u[2] = gmul2((f32x2){Sd1[0], Sd1[1]}, (f32x2){g3.x, g3.y});
                p2.u[3] = gmul2((f32x2){Sd1[2], Sd1[3]}, (f32x2){g3.z, g3.w});
                acc[3] = __builtin_amdgcn_mfma_f32_16x16x32_bf16(ax, p2.v, acc[3], 0, 0, 0);
            }
        }
    }

    // ---------- epilogue: O^T layout: lane (quad,lq): d2 = 4*quad+r, l = lq ----
    if (quad < 2) {
#pragma unroll
        for (int j = 0; j < 4; ++j) {
            const int lA  = wl0 + 16 * j + lq;
            const float sb = sbuf[wb][wseg * 64 + 16 * j + lq];
#pragma unroll
            for (int r = 0; r < 4; ++r) {
                const int ro = baseb + (4 * quad + r) * L + lA;
                out[ro] = acc[j][r] + x2[ro] * sb;
            }
        }
    }
}

extern "C" void kernel_launch(void* const* d_in, const int* in_sizes, int n_in,
                              void* d_out, int out_size, void* d_ws, size_t ws_size,
                              hipStream_t stream) {
    const float* v    = (const float*)d_in[0];
    const float* k    = (const float*)d_in[1];
    const float* bias = (const float*)d_in[2];
    const float* x1   = (const float*)d_in[3];
    const float* x2   = (const float*)d_in[4];
    float* out = (float*)d_out;

    const int D = in_sizes[2];            // 1024
    const int H = D / NHd;                // 128
    const int L = in_sizes[1] / H;        // 2048
    const int B = in_sizes[0] / (D * L);  // 2

    dim3 grid(H, L / 128);
    hyena_mfma20_kernel<<<grid, 256, 0, stream>>>(v, k, bias, x1, x2, out, B, H, L);
}